// Round 5
// baseline (4716.124 us; speedup 1.0000x reference)
//
#include <hip/hip_runtime.h>
#include <hip/hip_bf16.h>
#include <stdint.h>

#define BATCH 32
#define SEQT  512
#define DIM   256
#define UU    512
#define RING  4           // own-layer h ring slots

typedef __attribute__((ext_vector_type(8))) short bf16x8;
typedef __attribute__((ext_vector_type(4))) float f32x4;

__device__ __forceinline__ short f2bf(float f) {
  uint32_t u = __builtin_bit_cast(uint32_t, f);
  u += 0x7FFFu + ((u >> 16) & 1u);   // RNE
  return (short)(u >> 16);
}
__device__ __forceinline__ uint32_t pack2(float a, float b) {
  return ((uint32_t)(uint16_t)f2bf(b) << 16) | (uint16_t)f2bf(a);
}
__device__ __forceinline__ float sigm(float x) { return 1.0f / (1.0f + __expf(-x)); }
__device__ __forceinline__ float tanh_fast(float x) {
  float ax = fabsf(x);
  float t = __expf(-2.0f * ax);
  float r = (1.0f - t) / (1.0f + t);
  return copysignf(r, x);
}

// ---- flavored memory primitives ----
__device__ __forceinline__ void st_u32_plain(void* p, uint32_t v) {   // ack @ local L2
  asm volatile("global_store_dword %0, %1, off" :: "v"(p), "v"(v) : "memory");
}
__device__ __forceinline__ void st_u32_wt(void* p, uint32_t v) {      // write-through to LLC
  asm volatile("global_store_dword %0, %1, off sc0 sc1" :: "v"(p), "v"(v) : "memory");
}
__device__ __forceinline__ int ld_flag_l2(const int* p) {             // L1-bypass, local L2
  int v;
  asm volatile("global_load_dword %0, %1, off sc0\n\ts_waitcnt vmcnt(0)"
               : "=v"(v) : "v"(p) : "memory");
  return v;
}
__device__ __forceinline__ int ld_flag_l3(const int* p) {             // bypass to LLC
  int v;
  asm volatile("global_load_dword %0, %1, off sc0 sc1\n\ts_waitcnt vmcnt(0)"
               : "=v"(v) : "v"(p) : "memory");
  return v;
}
// 16B L1-bypass load, ISSUE-ONLY: must be followed by s_waitcnt vmcnt(0)+sched_barrier
__device__ __forceinline__ bf16x8 ld_b128_l2(const void* p) {
  bf16x8 v;
  asm volatile("global_load_dwordx4 %0, %1, off sc0" : "=&v"(v) : "v"(p) : "memory");
  return v;
}

#define VALVE (1 << 24)

// One layer's scan. 32 WGs/layer, all on ONE XCD (by ticket construction).
// WG jblk owns units [16*jblk,+16), wave=gate, all 32 batch rows.
template<int XSTEPS, bool XF32, bool LAST>
__device__ void scan_body(
    int jblk,
    const float* __restrict__ xf,       // [B][T][D] (layer 0)
    const short* __restrict__ Hxprev,   // prev layer cross buffer [T+1][32][512]
    short*       __restrict__ Hf,       // own ring [RING][32][512] (full if LAST)
    short*       __restrict__ Hx,       // cross out [T+1][32][512] (null if LAST)
    const float* __restrict__ W, const float* __restrict__ R,
    const float* __restrict__ bias,
    const float* __restrict__ hinit, const float* __restrict__ cinit,
    const int* cwPrev, int* cwOwn, int* progOwn,
    float (*zsm)[32][16])
{
  const int tid  = threadIdx.x;
  const int g    = tid >> 6;            // wave = gate (i,f,g,o)
  const int lane = tid & 63;
  const int arow = lane & 15;
  const int kq   = lane >> 4;
  const int jbase = jblk * 16;
  const int colg  = g * UU + jbase + arow;

  auto tileoff = [](int t) -> size_t {
    return (size_t)(LAST ? t : (t & (RING - 1))) * BATCH * UU;
  };

  // ---- one-time: weight B-fragments into registers ----
  bf16x8 bw[XSTEPS];
  bf16x8 br[16];
#pragma unroll
  for (int ks = 0; ks < XSTEPS; ++ks) {
    bf16x8 v;
#pragma unroll
    for (int jj = 0; jj < 8; ++jj)
      v[jj] = f2bf(W[(size_t)(ks * 32 + kq * 8 + jj) * 2048 + colg]);
    bw[ks] = v;
  }
#pragma unroll
  for (int ks = 0; ks < 16; ++ks) {
    bf16x8 v;
#pragma unroll
    for (int jj = 0; jj < 8; ++jj)
      v[jj] = f2bf(R[(size_t)(ks * 32 + kq * 8 + jj) * 2048 + colg]);
    br[ks] = v;
  }

  // ---- epilogue mapping: all threads compute rows (erowA, erowB) x unit pair;
  // waves 0,1 store Hf (plain); waves 2,3 store Hx (write-through)
  const int half  = tid >> 7;
  const int et    = tid & 127;
  const int epair = et & 7;
  const int erowA = et >> 3;            // 0..15
  const int erowB = erowA + 16;
  const int u0 = 2 * epair, u1 = u0 + 1;
  float biasv[4][2];
#pragma unroll
  for (int gg = 0; gg < 4; ++gg) {
    biasv[gg][0] = bias[gg * UU + jbase + u0];
    biasv[gg][1] = bias[gg * UU + jbase + u1];
  }
  float cA0 = cinit[jbase + u0], cA1 = cinit[jbase + u1];
  float cB0 = cA0, cB1 = cA1;

  // ---- init tile 0 ----
  {
    uint32_t pk = pack2(hinit[jbase + u0], hinit[jbase + u1]);
    if (half == 0) {
      short* p = Hf + tileoff(0) + jbase + u0;
      st_u32_plain(p + (size_t)erowA * UU, pk);
      st_u32_plain(p + (size_t)erowB * UU, pk);
    } else if (!LAST) {
      short* p = Hx + jbase + u0;
      st_u32_wt(p + (size_t)erowA * UU, pk);
      st_u32_wt(p + (size_t)erowB * UU, pk);
    }
  }
  asm volatile("s_waitcnt vmcnt(0)" ::: "memory");
  __syncthreads();
  if (tid == 0) {
    st_u32_plain(progOwn + jblk, 1);
    if (!LAST) st_u32_wt(cwOwn + jblk, 1);
  }

  int spins = 0;
  bool dead = false;   // valve: never hang — break out and finish with garbage

#pragma unroll 1
  for (int t = 0; t < SEQT; ++t) {
    // ---- cross poll: waves 0,1 only (their vmem queue is empty) ----
    if (!XF32 && g < 2 && !dead) {
      const int* pp = cwPrev + (lane & 31);
      const int need = t + 2;
      while (true) {
        int v = ld_flag_l3(pp);
        if (__all(v >= need)) break;
        __builtin_amdgcn_s_sleep(2);
        if (++spins > VALVE) { dead = true; break; }
      }
    }
    __syncthreads();   // B_cross: x-input attested for everyone

    f32x4 acc0 = {0.f, 0.f, 0.f, 0.f};
    f32x4 acc1 = {0.f, 0.f, 0.f, 0.f};

    // ---- x @ W ----
    if constexpr (XF32) {
      const float* p0 = xf + ((size_t)arow * SEQT + t) * DIM + kq * 8;
      const float* p1 = xf + ((size_t)(arow + 16) * SEQT + t) * DIM + kq * 8;
#pragma unroll
      for (int ks = 0; ks < XSTEPS; ++ks) {
        float4 x0 = *(const float4*)(p0 + ks * 32);
        float4 x1 = *(const float4*)(p0 + ks * 32 + 4);
        float4 y0 = *(const float4*)(p1 + ks * 32);
        float4 y1 = *(const float4*)(p1 + ks * 32 + 4);
        bf16x8 a0, a1;
        a0[0] = f2bf(x0.x); a0[1] = f2bf(x0.y); a0[2] = f2bf(x0.z); a0[3] = f2bf(x0.w);
        a0[4] = f2bf(x1.x); a0[5] = f2bf(x1.y); a0[6] = f2bf(x1.z); a0[7] = f2bf(x1.w);
        a1[0] = f2bf(y0.x); a1[1] = f2bf(y0.y); a1[2] = f2bf(y0.z); a1[3] = f2bf(y0.w);
        a1[4] = f2bf(y1.x); a1[5] = f2bf(y1.y); a1[6] = f2bf(y1.z); a1[7] = f2bf(y1.w);
        acc0 = __builtin_amdgcn_mfma_f32_16x16x32_bf16(a0, bw[ks], acc0, 0, 0, 0);
        acc1 = __builtin_amdgcn_mfma_f32_16x16x32_bf16(a1, bw[ks], acc1, 0, 0, 0);
      }
    } else {
      // prev layer's Hx: append-only, each address read once -> plain loads
      const short* xp = Hxprev + (size_t)(t + 1) * BATCH * UU + kq * 8;
#pragma unroll
      for (int ks = 0; ks < XSTEPS; ++ks) {
        bf16x8 a0 = *(const bf16x8*)(xp + (size_t)arow * UU + ks * 32);
        bf16x8 a1 = *(const bf16x8*)(xp + (size_t)(arow + 16) * UU + ks * 32);
        acc0 = __builtin_amdgcn_mfma_f32_16x16x32_bf16(a0, bw[ks], acc0, 0, 0, 0);
        acc1 = __builtin_amdgcn_mfma_f32_16x16x32_bf16(a1, bw[ks], acc1, 0, 0, 0);
      }
    }

    // ---- own poll (L2-scope; also drains waves 2,3's lazy Hx stores) ----
    if (!dead) {
      const int* pp = progOwn + (lane & 31);
      const int need = t + 1;
      while (true) {
        int v = ld_flag_l2(pp);
        if (__all(v >= need)) break;
        __builtin_amdgcn_s_sleep(1);
        if (++spins > VALVE) { dead = true; break; }
      }
    }

    // ---- h loads from ring slot (L1-bypass, local L2) ----
    bf16x8 ha[16], hb[16];
    {
      const short* hp = Hf + tileoff(t) + kq * 8;
#pragma unroll
      for (int ks = 0; ks < 16; ++ks) {
        ha[ks] = ld_b128_l2(hp + (size_t)arow * UU + ks * 32);
        hb[ks] = ld_b128_l2(hp + (size_t)(arow + 16) * UU + ks * 32);
      }
    }
    asm volatile("s_waitcnt vmcnt(0)" ::: "memory");
    __builtin_amdgcn_sched_barrier(0);

    // ---- h @ R ----
#pragma unroll
    for (int ks = 0; ks < 16; ++ks) {
      acc0 = __builtin_amdgcn_mfma_f32_16x16x32_bf16(ha[ks], br[ks], acc0, 0, 0, 0);
      acc1 = __builtin_amdgcn_mfma_f32_16x16x32_bf16(hb[ks], br[ks], acc1, 0, 0, 0);
    }

    // ---- exchange z across waves ----
#pragma unroll
    for (int r = 0; r < 4; ++r) {
      zsm[g][kq * 4 + r][arow]      = acc0[r];
      zsm[g][16 + kq * 4 + r][arow] = acc1[r];
    }
    __syncthreads();   // B_zsm

    // ---- gates + state (fp32), redundant across halves ----
    uint32_t pkA, pkB;
    {
      float zi0 = zsm[0][erowA][u0] + biasv[0][0];
      float zf0 = zsm[1][erowA][u0] + biasv[1][0];
      float zg0 = zsm[2][erowA][u0] + biasv[2][0];
      float zo0 = zsm[3][erowA][u0] + biasv[3][0];
      float zi1 = zsm[0][erowA][u1] + biasv[0][1];
      float zf1 = zsm[1][erowA][u1] + biasv[1][1];
      float zg1 = zsm[2][erowA][u1] + biasv[2][1];
      float zo1 = zsm[3][erowA][u1] + biasv[3][1];
      cA0 = sigm(zf0) * cA0 + sigm(zi0) * tanh_fast(zg0);
      cA1 = sigm(zf1) * cA1 + sigm(zi1) * tanh_fast(zg1);
      pkA = pack2(sigm(zo0) * tanh_fast(cA0), sigm(zo1) * tanh_fast(cA1));
    }
    {
      float zi0 = zsm[0][erowB][u0] + biasv[0][0];
      float zf0 = zsm[1][erowB][u0] + biasv[1][0];
      float zg0 = zsm[2][erowB][u0] + biasv[2][0];
      float zo0 = zsm[3][erowB][u0] + biasv[3][0];
      float zi1 = zsm[0][erowB][u1] + biasv[0][1];
      float zf1 = zsm[1][erowB][u1] + biasv[1][1];
      float zg1 = zsm[2][erowB][u1] + biasv[2][1];
      float zo1 = zsm[3][erowB][u1] + biasv[3][1];
      cB0 = sigm(zf0) * cB0 + sigm(zi0) * tanh_fast(zg0);
      cB1 = sigm(zf1) * cB1 + sigm(zi1) * tanh_fast(zg1);
      pkB = pack2(sigm(zo0) * tanh_fast(cB0), sigm(zo1) * tanh_fast(cB1));
    }

    // ---- split stores ----
    if (half == 0) {
      short* p = Hf + tileoff(t + 1) + jbase + u0;
      st_u32_plain(p + (size_t)erowA * UU, pkA);
      st_u32_plain(p + (size_t)erowB * UU, pkB);
    } else if (!LAST) {
      short* p = Hx + (size_t)(t + 1) * BATCH * UU + jbase + u0;
      st_u32_wt(p + (size_t)erowA * UU, pkA);
      st_u32_wt(p + (size_t)erowB * UU, pkB);
    }
    if (tid < 128) asm volatile("s_waitcnt vmcnt(0)" ::: "memory"); // Hf @ L2
    else           asm volatile("s_waitcnt vmcnt(2)" ::: "memory"); // lazy Hx
    __syncthreads();   // B_end
    if (tid == 0) {
      st_u32_plain(progOwn + jblk, t + 2);
      if (!LAST) st_u32_wt(cwOwn + jblk, t + 1);  // attests Hx tiles <= t
    }
  }

  asm volatile("s_waitcnt vmcnt(0)" ::: "memory");
  __syncthreads();
  if (!LAST && tid == 0) st_u32_wt(cwOwn + jblk, SEQT + 1);
}

__global__ __launch_bounds__(256, 1) void lstm_scan(
    const float* __restrict__ inputs,
    const float* __restrict__ W0, const float* __restrict__ R0, const float* __restrict__ b0,
    const float* __restrict__ h0i, const float* __restrict__ c0i,
    const float* __restrict__ W1, const float* __restrict__ R1, const float* __restrict__ b1,
    const float* __restrict__ h1i, const float* __restrict__ c1i,
    const float* __restrict__ W2, const float* __restrict__ R2, const float* __restrict__ b2,
    const float* __restrict__ h2i, const float* __restrict__ c2i,
    short* __restrict__ Hx0, short* __restrict__ Hx1, short* __restrict__ H2f,
    short* __restrict__ Hf0, short* __restrict__ Hf1,
    int* flags)
{
  __shared__ int s_layer, s_jblk;
  __shared__ float zsm[4][32][16];

  // ---- self-organizing role claim: XCD l hosts layer l (l<3) ----
  if (threadIdx.x == 0) {
    uint32_t xcc;
    asm volatile("s_getreg_b32 %0, hwreg(HW_REG_XCC_ID)" : "=s"(xcc));
    int lay = (int)(xcc & 7);
    int slot = -1;
    if (lay < 3)
      slot = __hip_atomic_fetch_add(&flags[lay], 1, __ATOMIC_RELAXED,
                                    __HIP_MEMORY_SCOPE_AGENT);
    s_layer = (slot >= 0 && slot < 32) ? lay : -1;
    s_jblk  = slot;
  }
  __syncthreads();
  const int layer = s_layer;
  const int jblk  = s_jblk;
  if (layer < 0) return;                // unclaimed block exits

  int* prog = flags + 128;              // 3 lines x 32 words (128B apart)
  int* cw   = flags + 384;              // 2 lines x 32 words

  if (layer == 0)
    scan_body<8,  true,  false>(jblk, inputs, nullptr, Hf0, Hx0,
                                W0, R0, b0, h0i, c0i, nullptr, cw, prog, zsm);
  else if (layer == 1)
    scan_body<16, false, false>(jblk, nullptr, Hx0, Hf1, Hx1,
                                W1, R1, b1, h1i, c1i, cw, cw + 32, prog + 32, zsm);
  else
    scan_body<16, false, true >(jblk, nullptr, Hx1, H2f, nullptr,
                                W2, R2, b2, h2i, c2i, cw + 32, nullptr, prog + 64, zsm);
}

// Y[b][t][:] = H2f[t+1][b][:] @ Wd + bd.  Tile: 128 rows x 64 cols per WG.
__global__ __launch_bounds__(256, 2) void dense_out(
    const short* __restrict__ H2,      // [T+1][32][512]
    const float* __restrict__ Wd,      // [512][256]
    const float* __restrict__ bd,      // [256]
    float* __restrict__ out)           // [32][512][256]
{
  const int mblock = blockIdx.x;       // 0..127
  const int nblock = blockIdx.y;       // 0..3
  const int tid  = threadIdx.x;
  const int wave = tid >> 6;
  const int lane = tid & 63;
  const int col  = lane & 15;
  const int kq   = lane >> 4;

  __shared__ short wlds[64][264];

  f32x4 acc[2][4];
#pragma unroll
  for (int mi = 0; mi < 2; ++mi)
#pragma unroll
    for (int ni = 0; ni < 4; ++ni)
      acc[mi][ni] = f32x4{0.f, 0.f, 0.f, 0.f};

  const short* Abase = H2 + (size_t)32 * UU;   // skip init tile

  for (int half = 0; half < 2; ++half) {
    __syncthreads();
    for (int idx = tid; idx < 256 * 64; idx += 256) {
      int k = idx >> 6;
      int c = idx & 63;
      wlds[c][k] = f2bf(Wd[(size_t)(half * 256 + k) * 256 + nblock * 64 + c]);
    }
    __syncthreads();
#pragma unroll
    for (int ks = 0; ks < 8; ++ks) {
      const int d0g = half * 256 + ks * 32 + kq * 8;
      const int d0l = ks * 32 + kq * 8;
      const size_t r0 = (size_t)(mblock * 128 + wave * 32 + col) * UU;
      const size_t r1 = (size_t)(mblock * 128 + wave * 32 + 16 + col) * UU;
      bf16x8 a0 = *(const bf16x8*)(Abase + r0 + d0g);
      bf16x8 a1 = *(const bf16x8*)(Abase + r1 + d0g);
#pragma unroll
      for (int ni = 0; ni < 4; ++ni) {
        bf16x8 bv = *(const bf16x8*)(&wlds[ni * 16 + col][d0l]);
        acc[0][ni] = __builtin_amdgcn_mfma_f32_16x16x32_bf16(a0, bv, acc[0][ni], 0, 0, 0);
        acc[1][ni] = __builtin_amdgcn_mfma_f32_16x16x32_bf16(a1, bv, acc[1][ni], 0, 0, 0);
      }
    }
  }

#pragma unroll
  for (int ni = 0; ni < 4; ++ni) {
    float bdv = bd[nblock * 64 + ni * 16 + col];
#pragma unroll
    for (int mi = 0; mi < 2; ++mi) {
#pragma unroll
      for (int r = 0; r < 4; ++r) {
        int grow = mblock * 128 + wave * 32 + mi * 16 + kq * 4 + r;
        int t = grow >> 5, b = grow & 31;
        out[((size_t)b * SEQT + t) * DIM + nblock * 64 + ni * 16 + col] = acc[mi][ni][r] + bdv;
      }
    }
  }
}

extern "C" void kernel_launch(void* const* d_in, const int* in_sizes, int n_in,
                              void* d_out, int out_size, void* d_ws, size_t ws_size,
                              hipStream_t stream) {
  const float* inputs = (const float*)d_in[0];
  const float* W0 = (const float*)d_in[1];
  const float* R0 = (const float*)d_in[2];
  const float* b0 = (const float*)d_in[3];
  const float* h0 = (const float*)d_in[4];
  const float* c0 = (const float*)d_in[5];
  const float* W1 = (const float*)d_in[6];
  const float* R1 = (const float*)d_in[7];
  const float* b1 = (const float*)d_in[8];
  const float* h1 = (const float*)d_in[9];
  const float* c1 = (const float*)d_in[10];
  const float* W2 = (const float*)d_in[11];
  const float* R2 = (const float*)d_in[12];
  const float* b2 = (const float*)d_in[13];
  const float* h2 = (const float*)d_in[14];
  const float* c2 = (const float*)d_in[15];
  const float* Wd = (const float*)d_in[16];
  const float* bd = (const float*)d_in[17];

  int* flags = (int*)d_ws;
  char* base = (char*)d_ws + 4096;
  const size_t HX  = (size_t)(SEQT + 1) * BATCH * UU * sizeof(short); // ~16.8 MB
  const size_t HFR = (size_t)RING * BATCH * UU * sizeof(short);       // 128 KB
  short* Hx0 = (short*)(base);
  short* Hx1 = (short*)(base + HX);
  short* H2f = (short*)(base + 2 * HX);
  short* Hf0 = (short*)(base + 3 * HX);
  short* Hf1 = (short*)(base + 3 * HX + HFR);

  hipMemsetAsync(d_ws, 0, 4096, stream);   // tickets + watermarks

  hipLaunchKernelGGL(lstm_scan, dim3(512), dim3(256), 0, stream,
                     inputs, W0, R0, b0, h0, c0, W1, R1, b1, h1, c1,
                     W2, R2, b2, h2, c2, Hx0, Hx1, H2f, Hf0, Hf1, flags);

  hipLaunchKernelGGL(dense_out, dim3(128, 4), dim3(256), 0, stream,
                     H2f, Wd, bd, (float*)d_out);
}

// Round 7
// 3080.588 us; speedup vs baseline: 1.5309x; 1.5309x over previous
//
#include <hip/hip_runtime.h>
#include <hip/hip_bf16.h>
#include <stdint.h>

#define BATCH 32
#define SEQT  512
#define DIM   256
#define UU    512

typedef __attribute__((ext_vector_type(8))) short bf16x8;
typedef __attribute__((ext_vector_type(4))) float f32x4;
typedef __attribute__((ext_vector_type(4))) unsigned int u32x4;

__device__ __forceinline__ short f2bf(float f) {
  uint32_t u = __builtin_bit_cast(uint32_t, f);
  u += 0x7FFFu + ((u >> 16) & 1u);   // RNE
  return (short)(u >> 16);
}
__device__ __forceinline__ uint32_t pack2(float a, float b) {
  return ((uint32_t)(uint16_t)f2bf(b) << 16) | (uint16_t)f2bf(a);
}
__device__ __forceinline__ float sigm(float x) { return 1.0f / (1.0f + __expf(-x)); }
__device__ __forceinline__ float tanh_fast(float x) {
  float ax = fabsf(x);
  float t = __expf(-2.0f * ax);
  float r = (1.0f - t) / (1.0f + t);
  return copysignf(r, x);
}

// 16B write-through store, visible at device coherence point after vmcnt drain.
// (Stores are safe as fire-and-forget asm; only asm LOADS had the spill hazard.)
__device__ __forceinline__ void st16_wt(void* p, u32x4 v) {
  asm volatile("global_store_dwordx4 %0, %1, off sc0 sc1" :: "v"(p), "v"(v) : "memory");
}

// One layer's persistent scan. Per layer: 64 WGs = 32 unit-blocks x 2 row-groups.
// WG owns 16 units x 16 batch rows; wave = gate. Weights live in registers.
// Sync: per-(layer,rowgroup) counter, fetch_add publish, relaxed-agent poll
// (round-2 proven semantics; h/x data read with plain loads after the barrier).
template<int XSTEPS, bool XF32>
__device__ void scan_body(
    int jblk, int rbase,
    const float* __restrict__ xf,       // [B][T][D] (layer 0 only)
    const short* __restrict__ Hprev,    // prev layer H [T+1][32][512]
    short*       __restrict__ Hown,     // own H [T+1][32][512]
    const float* __restrict__ W,        // [KX][2048]
    const float* __restrict__ R,        // [512][2048]
    const float* __restrict__ bias,     // [2048]
    const float* __restrict__ hinit,    // [512]
    const float* __restrict__ cinit,    // [512]
    const int* cntPrev, int* cntOwn)
{
  const int tid  = threadIdx.x;
  const int g    = tid >> 6;            // wave = gate (i,f,g,o)
  const int lane = tid & 63;
  const int arow = lane & 15;           // batch row (within 16) / unit col
  const int kq   = lane >> 4;
  const int jbase = jblk * 16;
  const int colg  = g * UU + jbase + arow;

  // ---- one-time: weight B-fragments into registers ----
  bf16x8 bw[XSTEPS];
  bf16x8 br[16];
#pragma unroll
  for (int ks = 0; ks < XSTEPS; ++ks) {
    bf16x8 v;
#pragma unroll
    for (int jj = 0; jj < 8; ++jj)
      v[jj] = f2bf(W[(size_t)(ks * 32 + kq * 8 + jj) * 2048 + colg]);
    bw[ks] = v;
  }
#pragma unroll
  for (int ks = 0; ks < 16; ++ks) {
    bf16x8 v;
#pragma unroll
    for (int jj = 0; jj < 8; ++jj)
      v[jj] = f2bf(R[(size_t)(ks * 32 + kq * 8 + jj) * 2048 + colg]);
    br[ks] = v;
  }

  // ---- epilogue mapping: threads 0..127 -> (row8 = 0..15, unit pair = 0..7) ----
  const int row8 = (tid & 127) >> 3;
  const int pair = tid & 7;
  const int u0 = 2 * pair, u1 = u0 + 1;
  float biasv[4][2];
#pragma unroll
  for (int gg = 0; gg < 4; ++gg) {
    biasv[gg][0] = bias[gg * UU + jbase + u0];
    biasv[gg][1] = bias[gg * UU + jbase + u1];
  }
  float cr0 = cinit[jbase + u0];
  float cr1 = cinit[jbase + u1];

  __shared__ float    zsm[4][16][16];
  __shared__ uint32_t hsm[16][8];       // packed bf16 pairs: 16 rows x 16 units

  // ---- init tile 0 ----
  if (tid < 128)
    hsm[row8][pair] = pack2(hinit[jbase + u0], hinit[jbase + u1]);
  __syncthreads();
  if (tid < 32) {
    int row = tid >> 1, q = tid & 1;
    u32x4 v = { hsm[row][q * 4 + 0], hsm[row][q * 4 + 1],
                hsm[row][q * 4 + 2], hsm[row][q * 4 + 3] };
    st16_wt(Hown + (size_t)(rbase + row) * UU + jbase + q * 8, v);
  }
  asm volatile("s_waitcnt vmcnt(0)" ::: "memory");
  __syncthreads();
  if (tid == 0)
    __hip_atomic_fetch_add(cntOwn, 1, __ATOMIC_RELAXED, __HIP_MEMORY_SCOPE_AGENT);

  int budget = 1 << 25;                 // termination valve (never hang)

#pragma unroll 1
  for (int t = 0; t < SEQT; ++t) {
    // ---- polls: tid0 only, cross then own; one barrier broadcasts ----
    if (tid == 0) {
      if constexpr (!XF32) {
        const int need = 32 * (t + 2);
        while (__hip_atomic_load(cntPrev, __ATOMIC_RELAXED,
                                 __HIP_MEMORY_SCOPE_AGENT) < need) {
          if (--budget < 0) break;
        }
      }
      const int need = 32 * (t + 1);
      while (__hip_atomic_load(cntOwn, __ATOMIC_RELAXED,
                               __HIP_MEMORY_SCOPE_AGENT) < need) {
        if (--budget < 0) break;
      }
    }
    __syncthreads();   // B_poll: inputs attested for everyone

    f32x4 acc = {0.f, 0.f, 0.f, 0.f};

    // ---- x @ W ----
    if constexpr (XF32) {
      const float* p = xf + ((size_t)(rbase + arow) * SEQT + t) * DIM + kq * 8;
#pragma unroll
      for (int ks = 0; ks < XSTEPS; ++ks) {
        float4 x0 = *(const float4*)(p + ks * 32);
        float4 x1 = *(const float4*)(p + ks * 32 + 4);
        bf16x8 a;
        a[0] = f2bf(x0.x); a[1] = f2bf(x0.y); a[2] = f2bf(x0.z); a[3] = f2bf(x0.w);
        a[4] = f2bf(x1.x); a[5] = f2bf(x1.y); a[6] = f2bf(x1.z); a[7] = f2bf(x1.w);
        acc = __builtin_amdgcn_mfma_f32_16x16x32_bf16(a, bw[ks], acc, 0, 0, 0);
      }
    } else {
      const short* xp = Hprev + ((size_t)(t + 1) * BATCH + rbase + arow) * UU + kq * 8;
#pragma unroll
      for (int ks = 0; ks < XSTEPS; ++ks) {
        bf16x8 a = *(const bf16x8*)(xp + ks * 32);
        acc = __builtin_amdgcn_mfma_f32_16x16x32_bf16(a, bw[ks], acc, 0, 0, 0);
      }
    }

    // ---- h @ R (plain loads; freshness guaranteed by poll + barrier) ----
    const short* hp = Hown + ((size_t)t * BATCH + rbase + arow) * UU + kq * 8;
#pragma unroll
    for (int ks = 0; ks < 16; ++ks) {
      bf16x8 a = *(const bf16x8*)(hp + ks * 32);
      acc = __builtin_amdgcn_mfma_f32_16x16x32_bf16(a, br[ks], acc, 0, 0, 0);
    }

    // ---- exchange z across waves (gates live in different waves) ----
#pragma unroll
    for (int r = 0; r < 4; ++r)
      zsm[g][kq * 4 + r][arow] = acc[r];
    __syncthreads();   // B_zsm

    // ---- gates + state (fp32): threads 0..127, 2 units each ----
    if (tid < 128) {
      float zi0 = zsm[0][row8][u0] + biasv[0][0];
      float zf0 = zsm[1][row8][u0] + biasv[1][0];
      float zg0 = zsm[2][row8][u0] + biasv[2][0];
      float zo0 = zsm[3][row8][u0] + biasv[3][0];
      float zi1 = zsm[0][row8][u1] + biasv[0][1];
      float zf1 = zsm[1][row8][u1] + biasv[1][1];
      float zg1 = zsm[2][row8][u1] + biasv[2][1];
      float zo1 = zsm[3][row8][u1] + biasv[3][1];
      cr0 = sigm(zf0) * cr0 + sigm(zi0) * tanh_fast(zg0);
      cr1 = sigm(zf1) * cr1 + sigm(zi1) * tanh_fast(zg1);
      hsm[row8][pair] = pack2(sigm(zo0) * tanh_fast(cr0),
                              sigm(zo1) * tanh_fast(cr1));
    }
    __syncthreads();   // B_h: hsm complete

    // ---- 32 x 16B write-through stores, then drain, then publish ----
    if (tid < 32) {
      int row = tid >> 1, q = tid & 1;
      u32x4 v = { hsm[row][q * 4 + 0], hsm[row][q * 4 + 1],
                  hsm[row][q * 4 + 2], hsm[row][q * 4 + 3] };
      st16_wt(Hown + ((size_t)(t + 1) * BATCH + rbase + row) * UU + jbase + q * 8, v);
    }
    asm volatile("s_waitcnt vmcnt(0)" ::: "memory");
    __syncthreads();   // B_end: all stores acked at coherence point
    if (tid == 0)
      __hip_atomic_fetch_add(cntOwn, 1, __ATOMIC_RELAXED, __HIP_MEMORY_SCOPE_AGENT);
  }
}

__global__ __launch_bounds__(256, 1) void lstm_scan(
    const float* __restrict__ inputs,
    const float* __restrict__ W0, const float* __restrict__ R0, const float* __restrict__ b0,
    const float* __restrict__ h0i, const float* __restrict__ c0i,
    const float* __restrict__ W1, const float* __restrict__ R1, const float* __restrict__ b1,
    const float* __restrict__ h1i, const float* __restrict__ c1i,
    const float* __restrict__ W2, const float* __restrict__ R2, const float* __restrict__ b2,
    const float* __restrict__ h2i, const float* __restrict__ c2i,
    short* __restrict__ H0, short* __restrict__ H1, short* __restrict__ H2,
    int* flags)
{
  const int layer = blockIdx.x >> 6;    // 0..2
  const int sub   = blockIdx.x & 63;
  const int jblk  = sub & 31;
  const int rblk  = sub >> 5;
  const int rbase = rblk * 16;

  int* cntOwn  = flags + (layer * 2 + rblk) * 32;          // 128B-spaced lines
  int* cntPrev = (layer > 0) ? flags + ((layer - 1) * 2 + rblk) * 32 : nullptr;

  if (layer == 0)
    scan_body<8,  true >(jblk, rbase, inputs, nullptr, H0,
                         W0, R0, b0, h0i, c0i, nullptr, cntOwn);
  else if (layer == 1)
    scan_body<16, false>(jblk, rbase, nullptr, H0, H1,
                         W1, R1, b1, h1i, c1i, cntPrev, cntOwn);
  else
    scan_body<16, false>(jblk, rbase, nullptr, H1, H2,
                         W2, R2, b2, h2i, c2i, cntPrev, cntOwn);
}

// Y[b][t][:] = H2[t+1][b][:] @ Wd + bd.  Tile: 128 rows x 64 cols per WG.
__global__ __launch_bounds__(256, 2) void dense_out(
    const short* __restrict__ H2,      // [T+1][32][512]
    const float* __restrict__ Wd,      // [512][256]
    const float* __restrict__ bd,      // [256]
    float* __restrict__ out)           // [32][512][256]
{
  const int mblock = blockIdx.x;       // 0..127
  const int nblock = blockIdx.y;       // 0..3
  const int tid  = threadIdx.x;
  const int wave = tid >> 6;
  const int lane = tid & 63;
  const int col  = lane & 15;
  const int kq   = lane >> 4;

  __shared__ short wlds[64][264];

  f32x4 acc[2][4];
#pragma unroll
  for (int mi = 0; mi < 2; ++mi)
#pragma unroll
    for (int ni = 0; ni < 4; ++ni)
      acc[mi][ni] = f32x4{0.f, 0.f, 0.f, 0.f};

  const short* Abase = H2 + (size_t)32 * UU;   // skip init tile

  for (int half = 0; half < 2; ++half) {
    __syncthreads();
    for (int idx = tid; idx < 256 * 64; idx += 256) {
      int k = idx >> 6;
      int c = idx & 63;
      wlds[c][k] = f2bf(Wd[(size_t)(half * 256 + k) * 256 + nblock * 64 + c]);
    }
    __syncthreads();
#pragma unroll
    for (int ks = 0; ks < 8; ++ks) {
      const int d0g = half * 256 + ks * 32 + kq * 8;
      const int d0l = ks * 32 + kq * 8;
      const size_t r0 = (size_t)(mblock * 128 + wave * 32 + col) * UU;
      const size_t r1 = (size_t)(mblock * 128 + wave * 32 + 16 + col) * UU;
      bf16x8 a0 = *(const bf16x8*)(Abase + r0 + d0g);
      bf16x8 a1 = *(const bf16x8*)(Abase + r1 + d0g);
#pragma unroll
      for (int ni = 0; ni < 4; ++ni) {
        bf16x8 bv = *(const bf16x8*)(&wlds[ni * 16 + col][d0l]);
        acc[0][ni] = __builtin_amdgcn_mfma_f32_16x16x32_bf16(a0, bv, acc[0][ni], 0, 0, 0);
        acc[1][ni] = __builtin_amdgcn_mfma_f32_16x16x32_bf16(a1, bv, acc[1][ni], 0, 0, 0);
      }
    }
  }

#pragma unroll
  for (int ni = 0; ni < 4; ++ni) {
    float bdv = bd[nblock * 64 + ni * 16 + col];
#pragma unroll
    for (int mi = 0; mi < 2; ++mi) {
#pragma unroll
      for (int r = 0; r < 4; ++r) {
        int grow = mblock * 128 + wave * 32 + mi * 16 + kq * 4 + r;
        int t = grow >> 5, b = grow & 31;
        out[((size_t)b * SEQT + t) * DIM + nblock * 64 + ni * 16 + col] = acc[mi][ni][r] + bdv;
      }
    }
  }
}

extern "C" void kernel_launch(void* const* d_in, const int* in_sizes, int n_in,
                              void* d_out, int out_size, void* d_ws, size_t ws_size,
                              hipStream_t stream) {
  const float* inputs = (const float*)d_in[0];
  const float* W0 = (const float*)d_in[1];
  const float* R0 = (const float*)d_in[2];
  const float* b0 = (const float*)d_in[3];
  const float* h0 = (const float*)d_in[4];
  const float* c0 = (const float*)d_in[5];
  const float* W1 = (const float*)d_in[6];
  const float* R1 = (const float*)d_in[7];
  const float* b1 = (const float*)d_in[8];
  const float* h1 = (const float*)d_in[9];
  const float* c1 = (const float*)d_in[10];
  const float* W2 = (const float*)d_in[11];
  const float* R2 = (const float*)d_in[12];
  const float* b2 = (const float*)d_in[13];
  const float* h2 = (const float*)d_in[14];
  const float* c2 = (const float*)d_in[15];
  const float* Wd = (const float*)d_in[16];
  const float* bd = (const float*)d_in[17];

  int* flags = (int*)d_ws;
  char* base = (char*)d_ws + 4096;
  const size_t HX = (size_t)(SEQT + 1) * BATCH * UU * sizeof(short); // ~16.8 MB
  short* H0 = (short*)(base);
  short* H1 = (short*)(base + HX);
  short* H2 = (short*)(base + 2 * HX);

  hipMemsetAsync(d_ws, 0, 4096, stream);   // counters = 0

  hipLaunchKernelGGL(lstm_scan, dim3(192), dim3(256), 0, stream,
                     inputs, W0, R0, b0, h0, c0, W1, R1, b1, h1, c1,
                     W2, R2, b2, h2, c2, H0, H1, H2, flags);

  hipLaunchKernelGGL(dense_out, dim3(128, 4), dim3(256), 0, stream,
                     H2, Wd, bd, (float*)d_out);
}

// Round 9
// 2690.642 us; speedup vs baseline: 1.7528x; 1.1449x over previous
//
#include <hip/hip_runtime.h>
#include <hip/hip_bf16.h>
#include <stdint.h>

#define BATCH 32
#define SEQT  512
#define DIM   256
#define UU    512
#define SENT  0x7FC07FC0u   // bf16 NaN pair: finite h/x data can never equal this

typedef __attribute__((ext_vector_type(8))) short bf16x8;
typedef __attribute__((ext_vector_type(4))) float f32x4;
typedef __attribute__((ext_vector_type(4))) unsigned int u32x4;

__device__ __forceinline__ short f2bf(float f) {
  uint32_t u = __builtin_bit_cast(uint32_t, f);
  u += 0x7FFFu + ((u >> 16) & 1u);   // RNE; finite in -> finite out (never NaN)
  return (short)(u >> 16);
}
__device__ __forceinline__ uint32_t pack2(float a, float b) {
  return ((uint32_t)(uint16_t)f2bf(b) << 16) | (uint16_t)f2bf(a);
}
__device__ __forceinline__ float sigm(float x) { return 1.0f / (1.0f + __expf(-x)); }
__device__ __forceinline__ float tanh_fast(float x) {
  float ax = fabsf(x);
  float t = __expf(-2.0f * ax);
  float r = (1.0f - t) / (1.0f + t);
  return copysignf(r, x);
}

// 16B write-through store (visible at LLC); fire-and-forget
__device__ __forceinline__ void st16_wt(void* p, u32x4 v) {
  asm volatile("global_store_dwordx4 %0, %1, off sc0 sc1" :: "v"(p), "v"(v) : "memory");
}

// ONE asm block: 16x 16B LLC-coherent loads off a single base + imm offsets,
// waitcnt INSIDE the block (safe pattern: no asm output is live across a wait).
// NOTE gfx950 syntax: offset: must precede cache flags -> "off offset:N sc0 sc1"
__device__ __forceinline__ void poll_load16(bf16x8 (&d)[16], const short* p) {
  asm volatile(
    "global_load_dwordx4 %0, %16, off sc0 sc1\n\t"
    "global_load_dwordx4 %1, %16, off offset:64 sc0 sc1\n\t"
    "global_load_dwordx4 %2, %16, off offset:128 sc0 sc1\n\t"
    "global_load_dwordx4 %3, %16, off offset:192 sc0 sc1\n\t"
    "global_load_dwordx4 %4, %16, off offset:256 sc0 sc1\n\t"
    "global_load_dwordx4 %5, %16, off offset:320 sc0 sc1\n\t"
    "global_load_dwordx4 %6, %16, off offset:384 sc0 sc1\n\t"
    "global_load_dwordx4 %7, %16, off offset:448 sc0 sc1\n\t"
    "global_load_dwordx4 %8, %16, off offset:512 sc0 sc1\n\t"
    "global_load_dwordx4 %9, %16, off offset:576 sc0 sc1\n\t"
    "global_load_dwordx4 %10, %16, off offset:640 sc0 sc1\n\t"
    "global_load_dwordx4 %11, %16, off offset:704 sc0 sc1\n\t"
    "global_load_dwordx4 %12, %16, off offset:768 sc0 sc1\n\t"
    "global_load_dwordx4 %13, %16, off offset:832 sc0 sc1\n\t"
    "global_load_dwordx4 %14, %16, off offset:896 sc0 sc1\n\t"
    "global_load_dwordx4 %15, %16, off offset:960 sc0 sc1\n\t"
    "s_waitcnt vmcnt(0)"
    : "=&v"(d[0]), "=&v"(d[1]), "=&v"(d[2]), "=&v"(d[3]),
      "=&v"(d[4]), "=&v"(d[5]), "=&v"(d[6]), "=&v"(d[7]),
      "=&v"(d[8]), "=&v"(d[9]), "=&v"(d[10]), "=&v"(d[11]),
      "=&v"(d[12]), "=&v"(d[13]), "=&v"(d[14]), "=&v"(d[15])
    : "v"(p)
    : "memory");
}

__device__ __forceinline__ int valid16(const bf16x8 (&a)[16]) {
  uint32_t ok = 1;
#pragma unroll
  for (int i = 0; i < 16; ++i) {
    u32x4 q = __builtin_bit_cast(u32x4, a[i]);
    ok &= (q[0] != SENT) & (q[1] != SENT) & (q[2] != SENT) & (q[3] != SENT);
  }
  return (int)ok;
}

// sentinel-fill the H buffers
__global__ void fill_sent(uint32_t* __restrict__ p, size_t n16) {
  u32x4 s = {SENT, SENT, SENT, SENT};
  for (size_t i = blockIdx.x * blockDim.x + threadIdx.x; i < n16;
       i += (size_t)gridDim.x * blockDim.x)
    st16_wt(p + i * 4, s);
}

// One layer's persistent scan. 64 WGs/layer = 32 unit-blocks x 2 row-groups;
// WG owns 16 units x 16 rows; wave = gate. All cross-WG sync is sentinel-polled
// data at the LLC: producers fire-and-forget, consumers poll+load in one RTT.
template<int XSTEPS, bool XF32>
__device__ void scan_body(
    int jblk, int rbase,
    const float* __restrict__ xf,       // [B][T][D] (layer 0 only)
    const short* __restrict__ Hprev,    // prev layer H [T+1][32][512]
    short*       __restrict__ Hown,     // own H [T+1][32][512]
    const float* __restrict__ W,        // [KX][2048]
    const float* __restrict__ R,        // [512][2048]
    const float* __restrict__ bias,     // [2048]
    const float* __restrict__ hinit,    // [512]
    const float* __restrict__ cinit)    // [512]
{
  const int tid  = threadIdx.x;
  const int g    = tid >> 6;            // wave = gate (i,f,g,o)
  const int lane = tid & 63;
  const int arow = lane & 15;           // batch row within group / unit col
  const int kq   = lane >> 4;
  const int jbase = jblk * 16;
  const int colg  = g * UU + jbase + arow;

  // ---- one-time: weight B-fragments into registers ----
  bf16x8 bw[XSTEPS];
  bf16x8 br[16];
#pragma unroll
  for (int ks = 0; ks < XSTEPS; ++ks) {
    bf16x8 v;
#pragma unroll
    for (int jj = 0; jj < 8; ++jj)
      v[jj] = f2bf(W[(size_t)(ks * 32 + kq * 8 + jj) * 2048 + colg]);
    bw[ks] = v;
  }
#pragma unroll
  for (int ks = 0; ks < 16; ++ks) {
    bf16x8 v;
#pragma unroll
    for (int jj = 0; jj < 8; ++jj)
      v[jj] = f2bf(R[(size_t)(ks * 32 + kq * 8 + jj) * 2048 + colg]);
    br[ks] = v;
  }

  // ---- epilogue mapping: threads 0..127 -> (row8, unit pair) ----
  const int row8 = (tid & 127) >> 3;
  const int pair = tid & 7;
  const int u0 = 2 * pair, u1 = u0 + 1;
  float biasv[4][2];
#pragma unroll
  for (int gg = 0; gg < 4; ++gg) {
    biasv[gg][0] = bias[gg * UU + jbase + u0];
    biasv[gg][1] = bias[gg * UU + jbase + u1];
  }
  float cr0 = cinit[jbase + u0];
  float cr1 = cinit[jbase + u1];

  __shared__ float    zsm[4][16][16];
  __shared__ uint32_t hsm[16][8];

  // ---- init tile 0: fire-and-forget ----
  if (tid < 128)
    hsm[row8][pair] = pack2(hinit[jbase + u0], hinit[jbase + u1]);
  __syncthreads();
  if (tid < 32) {
    int row = tid >> 1, q = tid & 1;
    u32x4 v = { hsm[row][q * 4 + 0], hsm[row][q * 4 + 1],
                hsm[row][q * 4 + 2], hsm[row][q * 4 + 3] };
    st16_wt(Hown + (size_t)(rbase + row) * UU + jbase + q * 8, v);
  }

  int budget = 1 << 18;                 // termination valve (never hang)

#pragma unroll 1
  for (int t = 0; t < SEQT; ++t) {
    f32x4 acc = {0.f, 0.f, 0.f, 0.f};

    // ---- x @ W ----
    if constexpr (XF32) {
      const float* p = xf + ((size_t)(rbase + arow) * SEQT + t) * DIM + kq * 8;
#pragma unroll
      for (int ks = 0; ks < XSTEPS; ++ks) {
        float4 x0 = *(const float4*)(p + ks * 32);
        float4 x1 = *(const float4*)(p + ks * 32 + 4);
        bf16x8 a;
        a[0] = f2bf(x0.x); a[1] = f2bf(x0.y); a[2] = f2bf(x0.z); a[3] = f2bf(x0.w);
        a[4] = f2bf(x1.x); a[5] = f2bf(x1.y); a[6] = f2bf(x1.z); a[7] = f2bf(x1.w);
        acc = __builtin_amdgcn_mfma_f32_16x16x32_bf16(a, bw[ks], acc, 0, 0, 0);
      }
    } else {
      // sentinel-poll prev layer's tile (has ~1 step of pipeline slack)
      bf16x8 xa[16];
      const short* xp = Hprev + ((size_t)(t + 1) * BATCH + rbase + arow) * UU + kq * 8;
      while (true) {
        poll_load16(xa, xp);
        if (__all(valid16(xa))) break;
        if (--budget < 0) break;
      }
#pragma unroll
      for (int ks = 0; ks < 16; ++ks)
        acc = __builtin_amdgcn_mfma_f32_16x16x32_bf16(xa[ks], bw[ks], acc, 0, 0, 0);
    }

    // ---- h @ R: sentinel-poll own tile t (detect+load = one RTT) ----
    {
      bf16x8 ha[16];
      const short* hp = Hown + ((size_t)t * BATCH + rbase + arow) * UU + kq * 8;
      while (true) {
        poll_load16(ha, hp);
        if (__all(valid16(ha))) break;
        if (--budget < 0) break;
      }
#pragma unroll
      for (int ks = 0; ks < 16; ++ks)
        acc = __builtin_amdgcn_mfma_f32_16x16x32_bf16(ha[ks], br[ks], acc, 0, 0, 0);
    }

    // ---- exchange z across waves (gates live in different waves) ----
#pragma unroll
    for (int r = 0; r < 4; ++r)
      zsm[g][kq * 4 + r][arow] = acc[r];
    __syncthreads();   // B_zsm

    // ---- gates + state (fp32): threads 0..127, 2 units each ----
    if (tid < 128) {
      float zi0 = zsm[0][row8][u0] + biasv[0][0];
      float zf0 = zsm[1][row8][u0] + biasv[1][0];
      float zg0 = zsm[2][row8][u0] + biasv[2][0];
      float zo0 = zsm[3][row8][u0] + biasv[3][0];
      float zi1 = zsm[0][row8][u1] + biasv[0][1];
      float zf1 = zsm[1][row8][u1] + biasv[1][1];
      float zg1 = zsm[2][row8][u1] + biasv[2][1];
      float zo1 = zsm[3][row8][u1] + biasv[3][1];
      cr0 = sigm(zf0) * cr0 + sigm(zi0) * tanh_fast(zg0);
      cr1 = sigm(zf1) * cr1 + sigm(zi1) * tanh_fast(zg1);
      hsm[row8][pair] = pack2(sigm(zo0) * tanh_fast(cr0),
                              sigm(zo1) * tanh_fast(cr1));
    }
    __syncthreads();   // B_h: hsm complete (also fences zsm reuse)

    // ---- 32 x 16B fire-and-forget stores; NO drain, NO publish ----
    if (tid < 32) {
      int row = tid >> 1, q = tid & 1;
      u32x4 v = { hsm[row][q * 4 + 0], hsm[row][q * 4 + 1],
                  hsm[row][q * 4 + 2], hsm[row][q * 4 + 3] };
      st16_wt(Hown + ((size_t)(t + 1) * BATCH + rbase + row) * UU + jbase + q * 8, v);
    }
  }
}

__global__ __launch_bounds__(256, 1) void lstm_scan(
    const float* __restrict__ inputs,
    const float* __restrict__ W0, const float* __restrict__ R0, const float* __restrict__ b0,
    const float* __restrict__ h0i, const float* __restrict__ c0i,
    const float* __restrict__ W1, const float* __restrict__ R1, const float* __restrict__ b1,
    const float* __restrict__ h1i, const float* __restrict__ c1i,
    const float* __restrict__ W2, const float* __restrict__ R2, const float* __restrict__ b2,
    const float* __restrict__ h2i, const float* __restrict__ c2i,
    short* __restrict__ H0, short* __restrict__ H1, short* __restrict__ H2)
{
  const int layer = blockIdx.x >> 6;    // 0..2
  const int sub   = blockIdx.x & 63;
  const int jblk  = sub & 31;
  const int rbase = (sub >> 5) * 16;

  if (layer == 0)
    scan_body<8,  true >(jblk, rbase, inputs, nullptr, H0, W0, R0, b0, h0i, c0i);
  else if (layer == 1)
    scan_body<16, false>(jblk, rbase, nullptr, H0, H1, W1, R1, b1, h1i, c1i);
  else
    scan_body<16, false>(jblk, rbase, nullptr, H1, H2, W2, R2, b2, h2i, c2i);
}

// Y[b][t][:] = H2[t+1][b][:] @ Wd + bd.  Tile: 128 rows x 64 cols per WG.
__global__ __launch_bounds__(256, 2) void dense_out(
    const short* __restrict__ H2,      // [T+1][32][512]
    const float* __restrict__ Wd,      // [512][256]
    const float* __restrict__ bd,      // [256]
    float* __restrict__ out)           // [32][512][256]
{
  const int mblock = blockIdx.x;       // 0..127
  const int nblock = blockIdx.y;       // 0..3
  const int tid  = threadIdx.x;
  const int wave = tid >> 6;
  const int lane = tid & 63;
  const int col  = lane & 15;
  const int kq   = lane >> 4;

  __shared__ short wlds[64][264];

  f32x4 acc[2][4];
#pragma unroll
  for (int mi = 0; mi < 2; ++mi)
#pragma unroll
    for (int ni = 0; ni < 4; ++ni)
      acc[mi][ni] = f32x4{0.f, 0.f, 0.f, 0.f};

  const short* Abase = H2 + (size_t)32 * UU;   // skip init tile

  for (int half = 0; half < 2; ++half) {
    __syncthreads();
    for (int idx = tid; idx < 256 * 64; idx += 256) {
      int k = idx >> 6;
      int c = idx & 63;
      wlds[c][k] = f2bf(Wd[(size_t)(half * 256 + k) * 256 + nblock * 64 + c]);
    }
    __syncthreads();
#pragma unroll
    for (int ks = 0; ks < 8; ++ks) {
      const int d0g = half * 256 + ks * 32 + kq * 8;
      const int d0l = ks * 32 + kq * 8;
      const size_t r0 = (size_t)(mblock * 128 + wave * 32 + col) * UU;
      const size_t r1 = (size_t)(mblock * 128 + wave * 32 + 16 + col) * UU;
      bf16x8 a0 = *(const bf16x8*)(Abase + r0 + d0g);
      bf16x8 a1 = *(const bf16x8*)(Abase + r1 + d0g);
#pragma unroll
      for (int ni = 0; ni < 4; ++ni) {
        bf16x8 bv = *(const bf16x8*)(&wlds[ni * 16 + col][d0l]);
        acc[0][ni] = __builtin_amdgcn_mfma_f32_16x16x32_bf16(a0, bv, acc[0][ni], 0, 0, 0);
        acc[1][ni] = __builtin_amdgcn_mfma_f32_16x16x32_bf16(a1, bv, acc[1][ni], 0, 0, 0);
      }
    }
  }

#pragma unroll
  for (int ni = 0; ni < 4; ++ni) {
    float bdv = bd[nblock * 64 + ni * 16 + col];
#pragma unroll
    for (int mi = 0; mi < 2; ++mi) {
#pragma unroll
      for (int r = 0; r < 4; ++r) {
        int grow = mblock * 128 + wave * 32 + mi * 16 + kq * 4 + r;
        int t = grow >> 5, b = grow & 31;
        out[((size_t)b * SEQT + t) * DIM + nblock * 64 + ni * 16 + col] = acc[mi][ni][r] + bdv;
      }
    }
  }
}

extern "C" void kernel_launch(void* const* d_in, const int* in_sizes, int n_in,
                              void* d_out, int out_size, void* d_ws, size_t ws_size,
                              hipStream_t stream) {
  const float* inputs = (const float*)d_in[0];
  const float* W0 = (const float*)d_in[1];
  const float* R0 = (const float*)d_in[2];
  const float* b0 = (const float*)d_in[3];
  const float* h0 = (const float*)d_in[4];
  const float* c0 = (const float*)d_in[5];
  const float* W1 = (const float*)d_in[6];
  const float* R1 = (const float*)d_in[7];
  const float* b1 = (const float*)d_in[8];
  const float* h1 = (const float*)d_in[9];
  const float* c1 = (const float*)d_in[10];
  const float* W2 = (const float*)d_in[11];
  const float* R2 = (const float*)d_in[12];
  const float* b2 = (const float*)d_in[13];
  const float* h2 = (const float*)d_in[14];
  const float* c2 = (const float*)d_in[15];
  const float* Wd = (const float*)d_in[16];
  const float* bd = (const float*)d_in[17];

  char* base = (char*)d_ws;
  const size_t HX = (size_t)(SEQT + 1) * BATCH * UU * sizeof(short); // ~16.8 MB
  short* H0 = (short*)(base);
  short* H1 = (short*)(base + HX);
  short* H2 = (short*)(base + 2 * HX);

  // re-arm sentinels every launch (replay-safe)
  const size_t n16 = 3 * HX / 16;
  hipLaunchKernelGGL(fill_sent, dim3(2048), dim3(256), 0, stream,
                     (uint32_t*)base, n16);

  hipLaunchKernelGGL(lstm_scan, dim3(192), dim3(256), 0, stream,
                     inputs, W0, R0, b0, h0, c0, W1, R1, b1, h1, c1,
                     W2, R2, b2, h2, c2, H0, H1, H2);

  hipLaunchKernelGGL(dense_out, dim3(128, 4), dim3(256), 0, stream,
                     H2, Wd, bd, (float*)d_out);
}